// Round 15
// baseline (94.177 us; speedup 1.0000x reference)
//
#include <hip/hip_runtime.h>
#include <hip/hip_bf16.h>

using bf16 = __hip_bfloat16;
typedef __attribute__((ext_vector_type(8))) short frag_ab;   // 8 bf16
typedef __attribute__((ext_vector_type(4))) float frag_cd;   // 4 fp32

constexpr float TEMP   = 0.07f;
constexpr float INVT   = 1.0f / TEMP;                 // fixed logsumexp shift
constexpr float THRESH = 0.1f;
constexpr float EPS    = 1e-8f;
constexpr float LOG2E  = 1.4426950408889634f;
constexpr float C1     = LOG2E / TEMP;                // exp((s-1)/T) = exp2(s*C1 - C1)

constexpr int D      = 128;
constexpr int SPLITS = 16;    // column splits -> grid (64,16) = 1024 blocks
constexpr int TI     = 128;   // rows per block (4 waves x 32 rows)
constexpr int TJ     = 32;    // cols per LDS tile: 2x8KB dbuf + 2KB labels = 18.4KB LDS
                              // -> LDS allows 8 blocks/CU; VGPR (~84, cap 85) allows 6
                              // waves/SIMD -> 6 blocks/CU = 1.5x champion's latency hiding.

__device__ __forceinline__ frag_cd mfma16(frag_ab a, frag_ab b, frag_cd c) {
    return __builtin_amdgcn_mfma_f32_16x16x32_bf16(a, b, c, 0, 0, 0);
}

// async global->LDS DMA, 16B per lane, LDS dest = wave-uniform base + lane*16
__device__ __forceinline__ void async_copy16(const bf16* gp, bf16* lp) {
    __builtin_amdgcn_global_load_lds(
        (__attribute__((address_space(1))) void*)(gp),
        (__attribute__((address_space(3))) void*)(lp), 16, 0, 0);
}

// ------- kernel 1: row-normalize -> bf16, diagonal dot, zero-init reduction cells -------
__global__ __launch_bounds__(256) void k1_normalize(
    const float* __restrict__ f, bf16* __restrict__ fn,
    float* __restrict__ diag, float* __restrict__ acc,
    unsigned* __restrict__ counter, int n)
{
    if (blockIdx.x == 0 && threadIdx.x == 0) { acc[0] = 0.f; counter[0] = 0u; }
    const int row  = blockIdx.x * 4 + (threadIdx.x >> 6);
    const int lane = threadIdx.x & 63;
    float2 v = ((const float2*)(f + (size_t)row * D))[lane];
    float ss = v.x * v.x + v.y * v.y;
    #pragma unroll
    for (int m = 32; m >= 1; m >>= 1) ss += __shfl_xor(ss, m, 64);
    const float inv = 1.0f / fmaxf(sqrtf(ss), EPS);
    __hip_bfloat162 o;
    o.x = __float2bfloat16(v.x * inv);
    o.y = __float2bfloat16(v.y * inv);
    ((__hip_bfloat162*)(fn + (size_t)row * D))[lane] = o;
    // diagonal raw dot of the bf16-rounded row (matches MFMA s_ii to ~1e-6)
    const float a = __bfloat162float(o.x), b = __bfloat162float(o.y);
    float p = a * a + b * b;
    #pragma unroll
    for (int m = 32; m >= 1; m >>= 1) p += __shfl_xor(p, m, 64);
    if (lane == 0) diag[row] = p;
}

// ---------------- kernel 2: fused sim + masked reductions ----------------
// R5 champion structure with ONE change: TJ 64->32 (LDS 34.8->18.4KB).
// LEDGER CORRECTION (R15): the prior "TJ=32 is worse" conclusion came from R2/R3,
// BOTH spill-contaminated (R2: forced 40-reg cap; R3: 64-reg cap vs ~85 live).
// Clean TJ=32 at (256,3) was never measured. Work here is IDENTICAL to champion
// (same ds_read/MFMA/epilogue/DMA-byte counts); only LDS residency changes:
// 4 blocks/CU (LDS-capped) -> 6 blocks/CU (VGPR-capped at 6 waves/SIMD).
// Cost: 17 barriers/block vs 9 — hidden by the 6-way inter-block overlap.
// LAUNCH-BOUNDS LAW (R0/R2/R4/R7 measured): arch-VGPR cap = 256/min_waves.
//   (256,3) -> 85 cap (champion: 84 used, no spill). DO NOT RAISE min_waves.
__global__ __launch_bounds__(256, 3) void k2_main(
    const bf16* __restrict__ fn, const float* __restrict__ lab,
    float* __restrict__ se_p, float* __restrict__ sp_p,
    float* __restrict__ cnt_p, int n)
{
    __shared__ float lab_s[512];             // cps = 8192/16
    __shared__ bf16  colbuf[2][TJ * D];      // col c, slot s holds source chunk s^(c&15)

    const int tid  = threadIdx.x;
    const int wave = tid >> 6;
    const int lane = tid & 63;
    const int quad = lane >> 4;
    const int l15  = lane & 15;

    const int cps    = n / SPLITS;        // 512
    const int cbase0 = blockIdx.y * cps;
    const int row_base = blockIdx.x * TI + wave * 32;

    for (int i = tid; i < cps; i += 256) lab_s[i] = lab[cbase0 + i];

    // A fragments: set s covers rows row_base + s*16 + l15, k = kb*32 + quad*8 + j
    frag_ab afr[2][4];
    #pragma unroll
    for (int s = 0; s < 2; ++s) {
        const bf16* ap = fn + (size_t)(row_base + s * 16 + l15) * D + quad * 8;
        #pragma unroll
        for (int kb = 0; kb < 4; ++kb) afr[s][kb] = *(const frag_ab*)(ap + kb * 32);
    }
    float li[2][4];
    #pragma unroll
    for (int s = 0; s < 2; ++s)
        #pragma unroll
        for (int r = 0; r < 4; ++r)
            li[s][r] = lab[row_base + s * 16 + quad * 4 + r];

    float se[2][4] = {}, sp[2][4] = {}, cnt[2][4] = {};

    // ---- DMA staging geometry (R3-verified, absmax 0): 2 issues/wave cover the 8KB tile ----
    // issue i, lane l: LDS byte = wave*2048 + i*1024 + l*16
    //   -> col c = wave*8 + i*4 + (l>>4), slot = l&15, source chunk = l15 ^ (c&15)
    int coloff[2];                        // bf16-unit src offset within the tile
    #pragma unroll
    for (int i = 0; i < 2; ++i) {
        const int ci = wave * 8 + i * 4 + (lane >> 4);
        const int ki = l15 ^ (ci & 15);
        coloff[i] = ci * D + ki * 8;
    }
    bf16* lbase[2] = { &colbuf[0][wave * 1024], &colbuf[1][wave * 1024] };

    const int ntiles = cps / TJ;  // 16
    const int jt0 = (blockIdx.x + blockIdx.y) & (ntiles - 1);  // convoy stagger

    // prologue: DMA tile jt0 -> buf[0]; barrier drains vmcnt (and covers lab_s)
    {
        const bf16* gt = fn + (size_t)(cbase0 + jt0 * TJ) * D;
        #pragma unroll
        for (int i = 0; i < 2; ++i)
            async_copy16(gt + coloff[i], lbase[0] + i * 512);
    }
    __syncthreads();

    for (int t = 0; t < ntiles; ++t) {
        const int cur = t & 1;
        const int jt  = (jt0 + t) & (ntiles - 1);
        // issue next tile's DMA NOW — lands in buf[cur^1] during this compute phase
        if (t + 1 < ntiles) {
            const int jn = (jt0 + t + 1) & (ntiles - 1);
            const bf16* gt = fn + (size_t)(cbase0 + jn * TJ) * D;
            #pragma unroll
            for (int i = 0; i < 2; ++i)
                async_copy16(gt + coloff[i], lbase[cur ^ 1] + i * 512);
        }

        #pragma unroll
        for (int sub = 0; sub < 2; ++sub) {
            const int c = sub * 16 + l15;          // column within tile
            frag_ab b[4];
            #pragma unroll
            for (int kb = 0; kb < 4; ++kb)
                b[kb] = *(const frag_ab*)(&colbuf[cur][(size_t)c * D + (((quad + 4 * kb) ^ l15) * 8)]);
            frag_cd a0 = {0.f, 0.f, 0.f, 0.f}, a1 = {0.f, 0.f, 0.f, 0.f};
            #pragma unroll
            for (int kb = 0; kb < 4; ++kb) {
                a0 = mfma16(afr[0][kb], b[kb], a0);
                a1 = mfma16(afr[1][kb], b[kb], a1);
            }
            const float lj = lab_s[jt * TJ + c];
            #pragma unroll
            for (int s = 0; s < 2; ++s) {
                const frag_cd& acc = s ? a1 : a0;
                #pragma unroll
                for (int r = 0; r < 4; ++r) {
                    const float sv = acc[r];                      // raw dot (cosine)
                    const float e  = __builtin_amdgcn_exp2f(__builtin_fmaf(sv, C1, -C1));
                    const float pm = (fabsf(li[s][r] - lj) < THRESH) ? 1.0f : 0.0f;
                    se[s][r]  += e;
                    sp[s][r]   = __builtin_fmaf(pm, sv, sp[s][r]); // raw dots; 1/T in k3
                    cnt[s][r] += pm;
                }
            }
        }

        // compiler emits s_waitcnt vmcnt(0) before s_barrier: buf[cur^1] fully landed
        // for t+1, and all waves done reading buf[cur] before its overwrite at t+1.
        __syncthreads();
    }

    // reduce across the 16 lanes of each quad-group (same rows, cols mod 16)
    #pragma unroll
    for (int s = 0; s < 2; ++s)
        #pragma unroll
        for (int r = 0; r < 4; ++r) {
            #pragma unroll
            for (int m = 1; m < 16; m <<= 1) {
                se[s][r]  += __shfl_xor(se[s][r],  m, 64);
                sp[s][r]  += __shfl_xor(sp[s][r],  m, 64);
                cnt[s][r] += __shfl_xor(cnt[s][r], m, 64);
            }
        }
    if (l15 == 0) {
        #pragma unroll
        for (int s = 0; s < 2; ++s)
            #pragma unroll
            for (int r = 0; r < 4; ++r) {
                const int i = row_base + s * 16 + quad * 4 + r;
                se_p[(size_t)blockIdx.y * n + i]  = se[s][r];
                sp_p[(size_t)blockIdx.y * n + i]  = sp[s][r];
                cnt_p[(size_t)blockIdx.y * n + i] = cnt[s][r];
            }
    }
}

// ------- kernel 3: per-row finalize + grid reduction (last-block pattern) -------
__global__ __launch_bounds__(256) void k3_finalize(
    const float* __restrict__ diag, const float* __restrict__ se_p,
    const float* __restrict__ sp_p, const float* __restrict__ cnt_p,
    float* __restrict__ acc, unsigned* __restrict__ counter,
    float* __restrict__ out, int n)
{
    const int row = blockIdx.x * 256 + threadIdx.x;
    float se = 0.f, sp = 0.f, cnt = 0.f;
    #pragma unroll
    for (int s = 0; s < SPLITS; ++s) {
        se  += se_p[(size_t)s * n + row];
        sp  += sp_p[(size_t)s * n + row];
        cnt += cnt_p[(size_t)s * n + row];
    }
    const float s_ii = diag[row];
    se  -= __builtin_amdgcn_exp2f(__builtin_fmaf(s_ii, C1, -C1));
    sp  -= s_ii;
    cnt -= 1.0f;
    float loss = INVT + __logf(se) - (sp * INVT) / fmaxf(cnt, 1.0f);

    // block reduce
    #pragma unroll
    for (int m = 32; m >= 1; m >>= 1) loss += __shfl_xor(loss, m, 64);
    __shared__ float wsum[4];
    if ((threadIdx.x & 63) == 0) wsum[threadIdx.x >> 6] = loss;
    __syncthreads();
    if (threadIdx.x == 0) {
        const float bs = wsum[0] + wsum[1] + wsum[2] + wsum[3];
        atomicAdd(acc, bs);
        __threadfence();
        const unsigned old = atomicAdd(counter, 1u);
        if (old == gridDim.x - 1) {
            const float total = atomicAdd(acc, 0.0f);  // atomic load, same-address order
            out[0] = total / (float)n;
        }
    }
}

extern "C" void kernel_launch(void* const* d_in, const int* in_sizes, int n_in,
                              void* d_out, int out_size, void* d_ws, size_t ws_size,
                              hipStream_t stream) {
    const float* feat = (const float*)d_in[0];
    const float* lab  = (const float*)d_in[1];
    const int n = in_sizes[1];              // 8192
    float* out = (float*)d_out;

    // ws: fn (n*D bf16 = 2MB) | diag | se_p | sp_p | cnt_p (each SPLITS*n f32) | acc | counter
    char* ws = (char*)d_ws;
    bf16* fn = (bf16*)ws;
    size_t off = (size_t)n * D * sizeof(bf16);
    float* diag  = (float*)(ws + off); off += (size_t)n * sizeof(float);
    float* se_p  = (float*)(ws + off); off += (size_t)SPLITS * n * sizeof(float);
    float* sp_p  = (float*)(ws + off); off += (size_t)SPLITS * n * sizeof(float);
    float* cnt_p = (float*)(ws + off); off += (size_t)SPLITS * n * sizeof(float);
    float* acc   = (float*)(ws + off); off += sizeof(float);
    unsigned* counter = (unsigned*)(ws + off);

    k1_normalize<<<n / 4, 256, 0, stream>>>(feat, fn, diag, acc, counter, n);
    dim3 g2(n / TI, SPLITS);
    k2_main<<<g2, 256, 0, stream>>>(fn, lab, se_p, sp_p, cnt_p, n);
    k3_finalize<<<n / 256, 256, 0, stream>>>(diag, se_p, sp_p, cnt_p, acc, counter, out, n);
}

// Round 16
// 93.740 us; speedup vs baseline: 1.0047x; 1.0047x over previous
//
#include <hip/hip_runtime.h>
#include <hip/hip_bf16.h>

using bf16 = __hip_bfloat16;
typedef __attribute__((ext_vector_type(8))) short frag_ab;   // 8 bf16
typedef __attribute__((ext_vector_type(4))) float frag_cd;   // 4 fp32

constexpr float TEMP   = 0.07f;
constexpr float INVT   = 1.0f / TEMP;                 // fixed logsumexp shift
constexpr float THRESH = 0.1f;
constexpr float EPS    = 1e-8f;
constexpr float LOG2E  = 1.4426950408889634f;
constexpr float C1     = LOG2E / TEMP;                // exp((s-1)/T) = exp2(s*C1 - C1)

constexpr int D      = 128;
constexpr int SPLITS = 16;    // column splits -> grid (64,16) = 1024 blocks (champion cfg)
constexpr int TI     = 128;   // rows per block (4 waves x 32 rows)
constexpr int TJ     = 64;    // cols per LDS tile

__device__ __forceinline__ frag_cd mfma16(frag_ab a, frag_ab b, frag_cd c) {
    return __builtin_amdgcn_mfma_f32_16x16x32_bf16(a, b, c, 0, 0, 0);
}

// async global->LDS DMA, 16B per lane, LDS dest = wave-uniform base + lane*16
__device__ __forceinline__ void async_copy16(const bf16* gp, bf16* lp) {
    __builtin_amdgcn_global_load_lds(
        (__attribute__((address_space(1))) void*)(gp),
        (__attribute__((address_space(3))) void*)(lp), 16, 0, 0);
}

// ------- kernel 1: row-normalize -> bf16, diagonal dot, zero-init reduction cells -------
__global__ __launch_bounds__(256) void k1_normalize(
    const float* __restrict__ f, bf16* __restrict__ fn,
    float* __restrict__ diag, float* __restrict__ acc,
    unsigned* __restrict__ counter, int n)
{
    if (blockIdx.x == 0 && threadIdx.x == 0) { acc[0] = 0.f; counter[0] = 0u; }
    const int row  = blockIdx.x * 4 + (threadIdx.x >> 6);
    const int lane = threadIdx.x & 63;
    float2 v = ((const float2*)(f + (size_t)row * D))[lane];
    float ss = v.x * v.x + v.y * v.y;
    #pragma unroll
    for (int m = 32; m >= 1; m >>= 1) ss += __shfl_xor(ss, m, 64);
    const float inv = 1.0f / fmaxf(sqrtf(ss), EPS);
    __hip_bfloat162 o;
    o.x = __float2bfloat16(v.x * inv);
    o.y = __float2bfloat16(v.y * inv);
    ((__hip_bfloat162*)(fn + (size_t)row * D))[lane] = o;
    // diagonal raw dot of the bf16-rounded row (matches MFMA s_ii to ~1e-6)
    const float a = __bfloat162float(o.x), b = __bfloat162float(o.y);
    float p = a * a + b * b;
    #pragma unroll
    for (int m = 32; m >= 1; m >>= 1) p += __shfl_xor(p, m, 64);
    if (lane == 0) diag[row] = p;
}

// ---------------- kernel 2: fused sim + masked reductions ----------------
// FINAL CHAMPION — measured 93.64 (R5), 93.51 (R14). TJ=64, SPLITS=16, double-
// buffered swizzled LDS, ONE barrier/tile, convoy stagger, global_load_lds DMA
// staging (m173 pre-swizzled-source: LDS dest linear per HW requirement, swizzle
// produced by pre-permuting each lane's GLOBAL source chunk).
//
// SESSION LEDGER — every alternative measured, none better:
//  - no-LDS streaming (R1): k2 69us (LDS sharing is load-bearing: 4x L2 traffic cut)
//  - TJ=32 clean at (256,3) (R15): 94.18 total — wash; extra barriers eat the
//    1.5x residency gain (R2/R3's TJ=32 losses were spill-confounded)
//  - forced occupancy via launch_bounds (R2/R4): VGPR collapse + scratch spill
//  - symmetric triangular tiling (R6-R12): halves MFMA, but all 6 delivery
//    mechanisms (global atomics / split stores / LDS atomics / private ds_writes
//    at 2 and 4 blocks/CU) landed k2 >= 38us vs this ~37us
//  - cnt hoisted to label-only k1 (R13): O(n^2) label scan costs more than it saves
// LAUNCH-BOUNDS LAW (measured R0/R2/R4/R7): arch-VGPR cap = 256/min_waves.
//   (256,3) -> 85 cap (84 used, no spill). (256,4)->64, (256,6)->40 both SPILL.
__global__ __launch_bounds__(256, 3) void k2_main(
    const bf16* __restrict__ fn, const float* __restrict__ lab,
    float* __restrict__ se_p, float* __restrict__ sp_p,
    float* __restrict__ cnt_p, int n)
{
    __shared__ float lab_s[512];             // cps = 8192/16
    __shared__ bf16  colbuf[2][TJ * D];      // col c, slot s holds source chunk s^(c&15)

    const int tid  = threadIdx.x;
    const int wave = tid >> 6;
    const int lane = tid & 63;
    const int quad = lane >> 4;
    const int l15  = lane & 15;

    const int cps    = n / SPLITS;        // 512
    const int cbase0 = blockIdx.y * cps;
    const int row_base = blockIdx.x * TI + wave * 32;

    for (int i = tid; i < cps; i += 256) lab_s[i] = lab[cbase0 + i];

    // A fragments: set s covers rows row_base + s*16 + l15, k = kb*32 + quad*8 + j
    frag_ab afr[2][4];
    #pragma unroll
    for (int s = 0; s < 2; ++s) {
        const bf16* ap = fn + (size_t)(row_base + s * 16 + l15) * D + quad * 8;
        #pragma unroll
        for (int kb = 0; kb < 4; ++kb) afr[s][kb] = *(const frag_ab*)(ap + kb * 32);
    }
    float li[2][4];
    #pragma unroll
    for (int s = 0; s < 2; ++s)
        #pragma unroll
        for (int r = 0; r < 4; ++r)
            li[s][r] = lab[row_base + s * 16 + quad * 4 + r];

    float se[2][4] = {}, sp[2][4] = {}, cnt[2][4] = {};

    // ---- DMA staging geometry: 4 issues/wave cover the 16KB tile ----
    // issue i, lane l: LDS byte = wave*4096 + i*1024 + l*16
    //   -> col c = wave*16 + i*4 + (l>>4), slot = l&15, source chunk k = l15 ^ (c&15)
    // (c&15 = i*4 + (l>>4) since wave*16 ≡ 0 mod 16)
    int coloff[4];                        // bf16-unit src offset within the tile
    #pragma unroll
    for (int i = 0; i < 4; ++i) {
        const int ci = wave * 16 + i * 4 + (lane >> 4);
        const int ki = l15 ^ (i * 4 + (lane >> 4));
        coloff[i] = ci * D + ki * 8;
    }
    bf16* lbase[2] = { &colbuf[0][wave * 2048], &colbuf[1][wave * 2048] };

    const int ntiles = cps / TJ;  // 8
    const int jt0 = (blockIdx.x + blockIdx.y) & (ntiles - 1);  // convoy stagger

    // prologue: DMA tile jt0 -> buf[0]; barrier drains vmcnt (and covers lab_s)
    {
        const bf16* gt = fn + (size_t)(cbase0 + jt0 * TJ) * D;
        #pragma unroll
        for (int i = 0; i < 4; ++i)
            async_copy16(gt + coloff[i], lbase[0] + i * 512);
    }
    __syncthreads();

    for (int t = 0; t < ntiles; ++t) {
        const int cur = t & 1;
        const int jt  = (jt0 + t) & (ntiles - 1);
        // issue next tile's DMA NOW — lands in buf[cur^1] during this compute phase
        if (t + 1 < ntiles) {
            const int jn = (jt0 + t + 1) & (ntiles - 1);
            const bf16* gt = fn + (size_t)(cbase0 + jn * TJ) * D;
            #pragma unroll
            for (int i = 0; i < 4; ++i)
                async_copy16(gt + coloff[i], lbase[cur ^ 1] + i * 512);
        }

        #pragma unroll
        for (int sub = 0; sub < 4; ++sub) {
            const int c = sub * 16 + l15;          // column within tile
            frag_ab b[4];
            #pragma unroll
            for (int kb = 0; kb < 4; ++kb)
                b[kb] = *(const frag_ab*)(&colbuf[cur][(size_t)c * D + (((quad + 4 * kb) ^ l15) * 8)]);
            frag_cd a0 = {0.f, 0.f, 0.f, 0.f}, a1 = {0.f, 0.f, 0.f, 0.f};
            #pragma unroll
            for (int kb = 0; kb < 4; ++kb) {
                a0 = mfma16(afr[0][kb], b[kb], a0);
                a1 = mfma16(afr[1][kb], b[kb], a1);
            }
            const float lj = lab_s[jt * TJ + c];
            #pragma unroll
            for (int s = 0; s < 2; ++s) {
                const frag_cd& acc = s ? a1 : a0;
                #pragma unroll
                for (int r = 0; r < 4; ++r) {
                    const float sv = acc[r];                      // raw dot (cosine)
                    const float e  = __builtin_amdgcn_exp2f(__builtin_fmaf(sv, C1, -C1));
                    const float pm = (fabsf(li[s][r] - lj) < THRESH) ? 1.0f : 0.0f;
                    se[s][r]  += e;
                    sp[s][r]   = __builtin_fmaf(pm, sv, sp[s][r]); // raw dots; 1/T in k3
                    cnt[s][r] += pm;
                }
            }
        }

        // compiler emits s_waitcnt vmcnt(0) before s_barrier: buf[cur^1] is fully
        // landed for t+1, and every wave is done reading buf[cur] before its
        // overwrite gets issued at the top of t+1.
        __syncthreads();
    }

    // reduce across the 16 lanes of each quad-group (same rows, cols mod 16)
    #pragma unroll
    for (int s = 0; s < 2; ++s)
        #pragma unroll
        for (int r = 0; r < 4; ++r) {
            #pragma unroll
            for (int m = 1; m < 16; m <<= 1) {
                se[s][r]  += __shfl_xor(se[s][r],  m, 64);
                sp[s][r]  += __shfl_xor(sp[s][r],  m, 64);
                cnt[s][r] += __shfl_xor(cnt[s][r], m, 64);
            }
        }
    if (l15 == 0) {
        #pragma unroll
        for (int s = 0; s < 2; ++s)
            #pragma unroll
            for (int r = 0; r < 4; ++r) {
                const int i = row_base + s * 16 + quad * 4 + r;
                se_p[(size_t)blockIdx.y * n + i]  = se[s][r];
                sp_p[(size_t)blockIdx.y * n + i]  = sp[s][r];
                cnt_p[(size_t)blockIdx.y * n + i] = cnt[s][r];
            }
    }
}

// ------- kernel 3: per-row finalize + grid reduction (last-block pattern) -------
__global__ __launch_bounds__(256) void k3_finalize(
    const float* __restrict__ diag, const float* __restrict__ se_p,
    const float* __restrict__ sp_p, const float* __restrict__ cnt_p,
    float* __restrict__ acc, unsigned* __restrict__ counter,
    float* __restrict__ out, int n)
{
    const int row = blockIdx.x * 256 + threadIdx.x;
    float se = 0.f, sp = 0.f, cnt = 0.f;
    #pragma unroll
    for (int s = 0; s < SPLITS; ++s) {
        se  += se_p[(size_t)s * n + row];
        sp  += sp_p[(size_t)s * n + row];
        cnt += cnt_p[(size_t)s * n + row];
    }
    const float s_ii = diag[row];
    se  -= __builtin_amdgcn_exp2f(__builtin_fmaf(s_ii, C1, -C1));
    sp  -= s_ii;
    cnt -= 1.0f;
    float loss = INVT + __logf(se) - (sp * INVT) / fmaxf(cnt, 1.0f);

    // block reduce
    #pragma unroll
    for (int m = 32; m >= 1; m >>= 1) loss += __shfl_xor(loss, m, 64);
    __shared__ float wsum[4];
    if ((threadIdx.x & 63) == 0) wsum[threadIdx.x >> 6] = loss;
    __syncthreads();
    if (threadIdx.x == 0) {
        const float bs = wsum[0] + wsum[1] + wsum[2] + wsum[3];
        atomicAdd(acc, bs);
        __threadfence();
        const unsigned old = atomicAdd(counter, 1u);
        if (old == gridDim.x - 1) {
            const float total = atomicAdd(acc, 0.0f);  // atomic load, same-address order
            out[0] = total / (float)n;
        }
    }
}

extern "C" void kernel_launch(void* const* d_in, const int* in_sizes, int n_in,
                              void* d_out, int out_size, void* d_ws, size_t ws_size,
                              hipStream_t stream) {
    const float* feat = (const float*)d_in[0];
    const float* lab  = (const float*)d_in[1];
    const int n = in_sizes[1];              // 8192
    float* out = (float*)d_out;

    // ws: fn (n*D bf16 = 2MB) | diag | se_p | sp_p | cnt_p (each SPLITS*n f32) | acc | counter
    char* ws = (char*)d_ws;
    bf16* fn = (bf16*)ws;
    size_t off = (size_t)n * D * sizeof(bf16);
    float* diag  = (float*)(ws + off); off += (size_t)n * sizeof(float);
    float* se_p  = (float*)(ws + off); off += (size_t)SPLITS * n * sizeof(float);
    float* sp_p  = (float*)(ws + off); off += (size_t)SPLITS * n * sizeof(float);
    float* cnt_p = (float*)(ws + off); off += (size_t)SPLITS * n * sizeof(float);
    float* acc   = (float*)(ws + off); off += sizeof(float);
    unsigned* counter = (unsigned*)(ws + off);

    k1_normalize<<<n / 4, 256, 0, stream>>>(feat, fn, diag, acc, counter, n);
    dim3 g2(n / TI, SPLITS);
    k2_main<<<g2, 256, 0, stream>>>(fn, lab, se_p, sp_p, cnt_p, n);
    k3_finalize<<<n / 256, 256, 0, stream>>>(diag, se_p, sp_p, cnt_p, acc, counter, out, n);
}